// Round 5
// baseline (997.754 us; speedup 1.0000x reference)
//
#include <hip/hip_runtime.h>
#include <cstdint>
#include <cstddef>

typedef unsigned short u16;
typedef __attribute__((ext_vector_type(8))) __bf16 bf16x8;
typedef __attribute__((ext_vector_type(4))) float f32x4;
typedef __attribute__((ext_vector_type(4))) unsigned int u32x4;

__device__ __forceinline__ float bf2f(u16 u){
  union { unsigned int i; float f; } x; x.i = ((unsigned int)u) << 16; return x.f;
}
__device__ __forceinline__ u16 f2bf(float f){
  union { float f; unsigned int i; } x; x.f = f;
  unsigned int i = x.i;
  return (u16)((i + 0x7fffu + ((i >> 16) & 1u)) >> 16);
}
__device__ __forceinline__ void load_lds16(const u16* g, u16* l){
  __builtin_amdgcn_global_load_lds((const __attribute__((address_space(1))) void*)g,
                                   (__attribute__((address_space(3))) void*)l, 16, 0, 0);
}

// ---------------- K0: transpose+cast 5 weights (1024x1024 f32 -> bf16 W^T) ----------------
__global__ __launch_bounds__(256) void k_transpose(
    const float* __restrict__ wh, const float* __restrict__ ww,
    const float* __restrict__ wd, const float* __restrict__ wc,
    const float* __restrict__ wp, u16* __restrict__ wT)
{
  __shared__ u16 tile[32][33];
  const float* src = (blockIdx.z==0)?wh:(blockIdx.z==1)?ww:(blockIdx.z==2)?wd:(blockIdx.z==3)?wc:wp;
  u16* dst = wT + (size_t)blockIdx.z * 1048576;
  int x = blockIdx.x*32 + threadIdx.x;
  int y0 = blockIdx.y*32;
  for (int i = threadIdx.y; i < 32; i += 8)
    tile[i][threadIdx.x] = f2bf(src[(size_t)(y0+i)*1024 + x]);
  __syncthreads();
  int x2 = y0 + threadIdx.x;
  int y2 = blockIdx.x*32;
  for (int i = threadIdx.y; i < 32; i += 8)
    dst[(size_t)(y2+i)*1024 + x2] = tile[threadIdx.x][i];
}

// ---------------- K1: partial sums over 2 axes (f32, exact) + fused x->bf16 cast ----------------
__global__ __launch_bounds__(256) void k_psum(
    const float* __restrict__ x, u16* __restrict__ xbf, float* __restrict__ P_h,
    float* __restrict__ PwP, float* __restrict__ PdP)
{
  const int b = blockIdx.x, cs = blockIdx.y, hg = blockIdx.z;
  const int th = threadIdx.x >> 7, tc = threadIdx.x & 127;
  const int h = hg*2 + th, c = cs*128 + tc;
  const size_t base = ((size_t)b<<22) + ((size_t)h<<18) + c;
  const float* xb = x + base;
  u16* xo = xbf + base;
  float sh = 0.f;
  float aW[16] = {}, aD[16] = {};
#pragma unroll
  for (int w = 0; w < 16; ++w)
#pragma unroll
    for (int d = 0; d < 16; ++d){
      float v = xb[(w<<14) + (d<<10)];
      xo[(w<<14) + (d<<10)] = f2bf(v);
      sh += v; aW[w] += v; aD[d] += v;
    }
  P_h[(size_t)((b<<4)+h)*1024 + c] = sh;
  const int part = hg*2 + th;     // 0..15
  float* pw = PwP + ((size_t)part<<17) + ((size_t)b<<14) + c;
  float* pd = PdP + ((size_t)part<<17) + ((size_t)b<<14) + c;
#pragma unroll
  for (int w = 0; w < 16; ++w) pw[w<<10] = aW[w];
#pragma unroll
  for (int d = 0; d < 16; ++d) pd[d<<10] = aD[d];
}

__global__ __launch_bounds__(256) void k_psum2(
    const float* __restrict__ PwP, const float* __restrict__ PdP,
    float* __restrict__ P_w, float* __restrict__ P_d)
{
  int idx = blockIdx.x*256 + threadIdx.x;   // 0..131071
  float s = 0.f, t = 0.f;
#pragma unroll
  for (int p = 0; p < 16; ++p){ s += PwP[(size_t)p*131072 + idx]; t += PdP[(size_t)p*131072 + idx]; }
  P_w[idx] = s; P_d[idx] = t;
}

// ---------------- K3: reduced weights  wred[j][k][S] = sum_i w_j[k][i*64+S] ----------------
__global__ __launch_bounds__(256) void k_wred(
    const float* __restrict__ wh, const float* __restrict__ ww, const float* __restrict__ wd,
    float* __restrict__ wred)
{
  const float* src = (blockIdx.y==0)?wh:(blockIdx.y==1)?ww:wd;
  int idx = blockIdx.x*256 + threadIdx.x;   // 0..65535
  int k = idx >> 6, S = idx & 63;
  float s = 0.f;
#pragma unroll
  for (int i = 0; i < 16; ++i) s += src[(size_t)k*1024 + i*64 + S];
  wred[(size_t)blockIdx.y*65536 + idx] = s;
}

// ---------------- K4: a_sum[b][c] = sum over positions of (h+w+d+c branches) ----------------
__global__ __launch_bounds__(256) void k_asum(
    const float* __restrict__ P_h, const float* __restrict__ P_w, const float* __restrict__ P_d,
    const float* __restrict__ wred, const float* __restrict__ wc,
    const float* __restrict__ bhv, const float* __restrict__ bwv,
    const float* __restrict__ bdv, const float* __restrict__ bcv,
    float* __restrict__ a_sum)
{
  const int b = blockIdx.x, cs = blockIdx.y, tid = threadIdx.x;
  const int tc = tid & 127, ti = tid >> 7;
  const int c = cs*128 + tc, sg = c >> 6, S = c & 63;
  __shared__ float xbar[1024];
  __shared__ float red[2][128];
  for (int k = tid; k < 1024; k += 256){
    float s = 0.f;
#pragma unroll
    for (int hh = 0; hh < 16; ++hh) s += P_h[(size_t)(b*16+hh)*1024 + k];
    xbar[k] = s;
  }
  __syncthreads();
  const float* Ph = P_h + (size_t)b*16384;
  const float* Pw = P_w + (size_t)b*16384;
  const float* Pd = P_d + (size_t)b*16384;
  const float* whr = wred, *wwr = wred + 65536, *wdr = wred + 131072;
  float acc = 0.f;
  for (int i = ti*8; i < ti*8 + 8; ++i){
#pragma unroll 8
    for (int si = 0; si < 64; ++si){
      int k = i*64 + si;
      acc += Ph[i*1024 + sg*64 + si] * whr[(size_t)k*64 + S]
           + Pw[i*1024 + sg*64 + si] * wwr[(size_t)k*64 + S]
           + Pd[i*1024 + sg*64 + si] * wdr[(size_t)k*64 + S];
    }
  }
#pragma unroll 8
  for (int k = ti*512; k < ti*512 + 512; ++k) acc += xbar[k] * wc[(size_t)k*1024 + c];
  red[ti][tc] = acc;
  __syncthreads();
  if (ti == 0){
    float bs = 0.f;
#pragma unroll
    for (int i = 0; i < 16; ++i) bs += bhv[i*64+S] + bwv[i*64+S] + bdv[i*64+S];
    a_sum[b*1024 + c] = red[0][tc] + red[1][tc] + 4096.f*bcv[c] + 256.f*bs;
  }
}

// ---------------- K5a: z1 = gelu(mean @ w1 + b1) ----------------
__global__ __launch_bounds__(256) void k_mlp1(
    const float* __restrict__ a_sum, const float* __restrict__ w1,
    const float* __restrict__ b1, float* __restrict__ z1g)
{
  const int b = blockIdx.x, tid = threadIdx.x;
  __shared__ float af[1024];
  for (int i = tid; i < 1024; i += 256) af[i] = a_sum[b*1024 + i] * (1.0f/4096.0f);
  __syncthreads();
  float acc = b1[tid];
#pragma unroll 8
  for (int k = 0; k < 1024; ++k) acc += af[k] * w1[(size_t)k*256 + tid];
  z1g[b*256 + tid] = 0.5f * acc * (1.0f + erff(acc * 0.70710678118654752f));
}

// ---------------- K5b: z2 = z1 @ w2 + b2 ; softmax over 4 branch slots ----------------
__global__ __launch_bounds__(128) void k_mlp2(
    const float* __restrict__ z1g, const float* __restrict__ w2,
    const float* __restrict__ b2, float* __restrict__ alpha)
{
  const int b = blockIdx.x, js = blockIdx.y, tid = threadIdx.x;
  __shared__ float z1[256];
  z1[tid] = z1g[b*256 + tid];
  z1[tid+128] = z1g[b*256 + tid + 128];
  __syncthreads();
  const int cch = js*128 + tid;       // channel 0..1023
  const int j0 = cch*4;
  f32x4 acc = *(const f32x4*)(b2 + j0);
#pragma unroll 8
  for (int k = 0; k < 256; ++k){
    f32x4 wv4 = *(const f32x4*)(w2 + (size_t)k*4096 + j0);
    float z = z1[k];
    acc[0] += z*wv4[0]; acc[1] += z*wv4[1]; acc[2] += z*wv4[2]; acc[3] += z*wv4[3];
  }
  float m = fmaxf(fmaxf(acc[0], acc[1]), fmaxf(acc[2], acc[3]));
  float e0 = expf(acc[0]-m), e1 = expf(acc[1]-m), e2 = expf(acc[2]-m), e3 = expf(acc[3]-m);
  float inv = 1.0f / (e0+e1+e2+e3);
  alpha[0*8192 + b*1024 + cch] = e0*inv;
  alpha[1*8192 + b*1024 + cch] = e1*inv;
  alpha[2*8192 + b*1024 + cch] = e2*inv;
  alpha[3*8192 + b*1024 + cch] = e3*inv;
}

// ============ 256x256 8-phase GEMM template, T2 XOR-swizzled LDS, PERSISTENT blocks ============
// LDS slot(row,chunk16B) = row*64B + (chunk ^ ((row>>1)&3))*16B; linear writes (global_load_lds),
// source-preswizzled global chunk, same XOR on ds_read (G21). vmcnt counted, never 0 mid-loop.
// Persistent: each block owns several tiles; last main-loop iter is peeled (no useless stages,
// vmcnt(0) drain), next tile's 12 prologue loads are issued BEFORE the epilogue stores so the
// stores hide the HBM latency; one vmcnt(4)+barrier replaces the old inter-kernel drain.

#define STAGE_A(buf, kk, kt) \
  load_lds16(gA0 + (size_t)(kt)*strideK + (kk)*32, sA + (buf)*16384 + (kk)*8192); \
  load_lds16(gA1 + (size_t)(kt)*strideK + (kk)*32, sA + (buf)*16384 + (kk)*8192 + 4096)
#define STAGE_B(buf, kk, kt) \
  load_lds16(gB0 + (kt)*64 + (kk)*32, sB + (buf)*16384 + (kk)*8192); \
  load_lds16(gB1 + (kt)*64 + (kk)*32, sB + (buf)*16384 + (kk)*8192 + 4096)

#define PHASE(h, kk, buf, STAGE_STMT, VM) do{ \
  const u16* ar_ = ldsA + (buf)*16384 + (kk)*8192 + ardoff + (h)*2048; \
  const u16* br_ = ldsB + (buf)*16384 + (kk)*8192 + brdoff; \
  bf16x8 af_[4], bf_[4]; \
  _Pragma("unroll") for (int m_ = 0; m_ < 4; ++m_) af_[m_] = *(const bf16x8*)(ar_ + m_*512); \
  _Pragma("unroll") for (int n_ = 0; n_ < 4; ++n_) bf_[n_] = *(const bf16x8*)(br_ + n_*512); \
  STAGE_STMT; \
  if (VM == 1) asm volatile("s_waitcnt vmcnt(4)" ::: "memory"); \
  if (VM == 2) asm volatile("s_waitcnt vmcnt(0)" ::: "memory"); \
  __builtin_amdgcn_s_barrier(); \
  asm volatile("s_waitcnt lgkmcnt(0)" ::: "memory"); \
  __builtin_amdgcn_sched_barrier(0); \
  __builtin_amdgcn_s_setprio(1); \
  _Pragma("unroll") for (int m_ = 0; m_ < 4; ++m_) \
    _Pragma("unroll") for (int n_ = 0; n_ < 4; ++n_) \
      acc[(h)*4+m_][n_] = __builtin_amdgcn_mfma_f32_16x16x32_bf16(af_[m_], bf_[n_], acc[(h)*4+m_][n_], 0, 0, 0); \
  __builtin_amdgcn_s_setprio(0); \
  __builtin_amdgcn_s_barrier(); \
}while(0)

#define STAGE12() do{ \
  load_lds16(gA0, sA);                 load_lds16(gA1, sA + 4096); \
  load_lds16(gB0, sB);                 load_lds16(gB1, sB + 4096); \
  load_lds16(gA0 + 32, sA + 8192);     load_lds16(gA1 + 32, sA + 8192 + 4096); \
  load_lds16(gB0 + 32, sB + 8192);     load_lds16(gB1 + 32, sB + 8192 + 4096); \
  load_lds16(gA0 + strideK, sA + 16384);   load_lds16(gA1 + strideK, sA + 16384 + 4096); \
  load_lds16(gB0 + 64, sB + 16384);        load_lds16(gB1 + 64, sB + 16384 + 4096); \
}while(0)

#define GEMM_ITERS06() \
  for (int i = 0; i < 7; ++i){ \
    const int t1 = 2*i + 1, t2 = 2*i + 2, t3 = 2*i + 3; \
    PHASE(0,0,0, STAGE_A(1,1,t1), 0); \
    PHASE(1,0,0, STAGE_B(1,1,t1), 0); \
    PHASE(0,1,0, STAGE_A(0,0,t2), 0); \
    PHASE(1,1,0, STAGE_B(0,0,t2), 1); \
    PHASE(0,0,1, STAGE_A(0,1,t2), 0); \
    PHASE(1,0,1, STAGE_B(0,1,t2), 0); \
    PHASE(0,1,1, STAGE_A(1,0,t3), 0); \
    PHASE(1,1,1, STAGE_B(1,0,t3), 1); \
  }

#define GEMM_ITER7() \
  PHASE(0,0,0, STAGE_A(1,1,15), 0); \
  PHASE(1,0,0, STAGE_B(1,1,15), 0); \
  PHASE(0,1,0, (void)0, 0); \
  PHASE(1,1,0, (void)0, 2); \
  PHASE(0,0,1, (void)0, 0); \
  PHASE(1,0,1, (void)0, 0); \
  PHASE(0,1,1, (void)0, 0); \
  PHASE(1,1,1, (void)0, 0);

// ---------------- K6: branch GEMMs (h,w,d,c), persistent 8 tiles/block ----------------
__device__ __forceinline__ void branch_abase(int branch, int rtile, int wv,
                                             size_t& cb0, size_t& cb1){
  const int q1 = rtile & 15, b_ = rtile >> 4;
  const size_t q2a = wv, q2b = wv + 8;
  if      (branch == 0){ cb0 = ((size_t)b_<<22) + (q2a<<14) + ((size_t)q1<<6);
                         cb1 = ((size_t)b_<<22) + (q2b<<14) + ((size_t)q1<<6); }
  else if (branch == 1){ cb0 = ((size_t)b_<<22) + ((size_t)q1<<18) + (q2a<<6);
                         cb1 = ((size_t)b_<<22) + ((size_t)q1<<18) + (q2b<<6); }
  else if (branch == 2){ cb0 = ((size_t)b_<<22) + ((size_t)q1<<18) + (q2a<<14);
                         cb1 = ((size_t)b_<<22) + ((size_t)q1<<18) + (q2b<<14); }
  else { size_t r0 = (size_t)(rtile*256 + wv*16); cb0 = r0 << 10; cb1 = (r0+128) << 10; }
}

__global__ __launch_bounds__(512, 2) void k_branch_gemm(
    const u16* __restrict__ xbf, const u16* __restrict__ wT,
    const float* __restrict__ bh, const float* __restrict__ bw,
    const float* __restrict__ bd, const float* __restrict__ bc,
    u16* __restrict__ hbuf, u16* __restrict__ wbuf,
    u16* __restrict__ dbuf, u16* __restrict__ cbuf)
{
  // 256 persistent blocks; block p -> XCD p&7; tiles id = xcd*256 + slot + j*32 (j=0..7):
  // branch, ntile fixed per block (B-panel + bias hoisted); rtile walks by +8.
  const int p = blockIdx.x;
  const int xcd = p & 7, slot = p >> 3;
  const int id0 = xcd*256 + slot;
  const int ntile  = id0 & 3;
  const int branch = id0 >> 9;

  const int tid = threadIdx.x;
  const int wv = tid >> 6, l = tid & 63;

  __shared__ __align__(16) u16 ldsA[32768];   // 64 KiB
  __shared__ __align__(16) u16 ldsB[32768];   // 64 KiB

  const u16* wsel = wT + (size_t)branch * 1048576;
  const float* bias = (branch==0)?bh:(branch==1)?bw:(branch==2)?bd:bc;
  u16* obuf         = (branch==0)?hbuf:(branch==1)?wbuf:(branch==2)?dbuf:cbuf;

  const int lr = l >> 2;
  const int qg = ((l & 3) ^ ((lr >> 1) & 3)) * 8;   // T2 swizzle on global source
  const int strideK = (branch==0)?262144:(branch==1)?16384:(branch==2)?1024:64;
  const int rsh = (branch == 2) ? 6 : 10;

  const u16* gB0 = wsel + (size_t)(ntile*256 + wv*16 + lr) * 1024 + qg;
  const u16* gB1 = gB0 + 128*1024;
  u16* sA = ldsA + wv*512;
  u16* sB = ldsB + wv*512;

  const int wm = wv >> 2, wn = wv & 3;
  const int fr = l & 15;
  const int cswz = ((l >> 4) ^ ((fr >> 1) & 3)) * 8;
  const int ardoff = (wm*128 + fr)*32 + cswz;
  const int brdoff = (wn*64  + fr)*32 + cswz;

  // hoisted bias (ntile fixed):
  float bv4[4];
#pragma unroll
  for (int nf = 0; nf < 4; ++nf) bv4[nf] = bias[ntile*256 + wn*64 + nf*16 + fr];
  // canonical-layout shift tuple:
  int sc, s1, s2, s3;
  if      (branch==0){ sc=18; s1=6;  s2=14; s3=10; }
  else if (branch==1){ sc=14; s1=18; s2=6;  s3=10; }
  else if (branch==2){ sc=10; s1=18; s2=14; s3=6;  }
  else               { sc=6;  s1=18; s2=14; s3=10; }

  // tile 0 addresses + prologue
  int rtile = (id0 >> 2) & 127;
  size_t cb0, cb1;
  branch_abase(branch, rtile, wv, cb0, cb1);
  const u16* gA0 = xbf + cb0 + ((size_t)lr << rsh) + qg;
  const u16* gA1 = xbf + cb1 + ((size_t)lr << rsh) + qg;
  STAGE12();
  asm volatile("s_waitcnt vmcnt(4)" ::: "memory");
  __builtin_amdgcn_s_barrier();

  for (int j = 0; j < 8; ++j){
    if (j){
      asm volatile("s_waitcnt vmcnt(4)" ::: "memory");
      __builtin_amdgcn_s_barrier();
    }
    f32x4 acc[8][4] = {};
    GEMM_ITERS06();
    GEMM_ITER7();
    const int rtile_cur = rtile;
    if (j < 7){
      rtile = ((id0 + (j+1)*32) >> 2) & 127;
      branch_abase(branch, rtile, wv, cb0, cb1);
      gA0 = xbf + cb0 + ((size_t)lr << rsh) + qg;
      gA1 = xbf + cb1 + ((size_t)lr << rsh) + qg;
      STAGE12();                 // next tile's prologue loads, in flight during epilogue
    }
    // epilogue tile j: canonical position-major layout
    const int bb_ = rtile_cur >> 4, p1 = rtile_cur & 15;
#pragma unroll
    for (int mg = 0; mg < 8; ++mg){
      const int p2 = wm*8 + mg;
#pragma unroll
      for (int nf = 0; nf < 4; ++nf){
        int col = ntile*256 + wn*64 + nf*16 + fr;
        int ch = col >> 6, cl = col & 63;
        size_t base = ((size_t)bb_<<22) | ((size_t)p1<<s1) | ((size_t)ch<<sc)
                    | ((size_t)p2<<s2) | (size_t)cl;
#pragma unroll
        for (int rg = 0; rg < 4; ++rg){
          int p3 = (l>>4)*4 + rg;
          obuf[base + ((size_t)p3<<s3)] = f2bf(acc[mg][nf][rg] + bv4[nf]);
        }
      }
    }
  }
}

// ---------------- K7: mix = a0*h + a1*w + a2*d + a3*c -> bf16 (all canonical, pure stream) ----------------
__global__ __launch_bounds__(256) void k_mix(
    const u16* __restrict__ hbuf, const u16* __restrict__ wbuf,
    const u16* __restrict__ dbuf, const u16* __restrict__ cbuf,
    u16* __restrict__ mix, const float* __restrict__ alpha)
{
  int idx = blockIdx.x*256 + threadIdx.x;   // 0..4194303
  int p  = idx >> 7;
  int c0 = (idx & 127) << 3;
  int b = p >> 12;
  size_t off = ((size_t)p << 10) + c0;
  union { u32x4 v; u16 u[8]; } hv, wv, dv, cv, mv;
  hv.v = *(const u32x4*)(hbuf + off);
  wv.v = *(const u32x4*)(wbuf + off);
  dv.v = *(const u32x4*)(dbuf + off);
  cv.v = *(const u32x4*)(cbuf + off);
  union { f32x4 f[2]; float a[8]; } a0, a1, a2, a3;
  const float* ab = alpha + b*1024 + c0;
  a0.f[0] = *(const f32x4*)(ab);         a0.f[1] = *(const f32x4*)(ab + 4);
  a1.f[0] = *(const f32x4*)(ab + 8192);  a1.f[1] = *(const f32x4*)(ab + 8196);
  a2.f[0] = *(const f32x4*)(ab + 16384); a2.f[1] = *(const f32x4*)(ab + 16388);
  a3.f[0] = *(const f32x4*)(ab + 24576); a3.f[1] = *(const f32x4*)(ab + 24580);
#pragma unroll
  for (int e = 0; e < 8; ++e){
    float m = a0.a[e]*bf2f(hv.u[e]) + a1.a[e]*bf2f(wv.u[e])
            + a2.a[e]*bf2f(dv.u[e]) + a3.a[e]*bf2f(cv.u[e]);
    mv.u[e] = f2bf(m);
  }
  *(u32x4*)(mix + off) = mv.v;
}

// ---------------- K8: out(f32) = mix(bf16) @ wp + bp  (persistent, 2 tiles/block) ----------------
__global__ __launch_bounds__(512, 2) void k_final_gemm(
    const u16* __restrict__ A, const u16* __restrict__ wpT,
    const float* __restrict__ bp, float* __restrict__ out)
{
  // 256 blocks; tiles id = xcd*64 + slot*2 + j (j=0,1): rtile fixed (A reused), ntile flips.
  const int p = blockIdx.x;
  const int xcd = p & 7, slot = p >> 3;
  const int id0 = xcd*64 + slot*2;
  const int rtile = id0 >> 2;

  const int tid = threadIdx.x;
  const int wv = tid >> 6, l = tid & 63;

  __shared__ __align__(16) u16 ldsA[32768];
  __shared__ __align__(16) u16 ldsB[32768];

  const int lr = l >> 2;
  const int qg = ((l & 3) ^ ((lr >> 1) & 3)) * 8;
  const int strideK = 64;
  const size_t r0 = (size_t)(rtile*256 + wv*16);
  const u16* gA0 = A + (r0 << 10) + ((size_t)lr << 10) + qg;
  const u16* gA1 = A + ((r0 + 128) << 10) + ((size_t)lr << 10) + qg;
  int ntile = id0 & 3;
  const u16* gB0 = wpT + (size_t)(ntile*256 + wv*16 + lr) * 1024 + qg;
  const u16* gB1 = gB0 + 128*1024;
  u16* sA = ldsA + wv*512;
  u16* sB = ldsB + wv*512;

  const int wm = wv >> 2, wn = wv & 3;
  const int fr = l & 15;
  const int cswz = ((l >> 4) ^ ((fr >> 1) & 3)) * 8;
  const int ardoff = (wm*128 + fr)*32 + cswz;
  const int brdoff = (wn*64  + fr)*32 + cswz;

  STAGE12();
  asm volatile("s_waitcnt vmcnt(4)" ::: "memory");
  __builtin_amdgcn_s_barrier();

  for (int j = 0; j < 2; ++j){
    if (j){
      asm volatile("s_waitcnt vmcnt(4)" ::: "memory");
      __builtin_amdgcn_s_barrier();
    }
    f32x4 acc[8][4] = {};
    GEMM_ITERS06();
    GEMM_ITER7();
    const int ntile_cur = ntile;
    if (j < 1){
      ntile = (id0 + 1) & 3;
      gB0 = wpT + (size_t)(ntile*256 + wv*16 + lr) * 1024 + qg;
      gB1 = gB0 + 128*1024;
      STAGE12();
    }
#pragma unroll
    for (int mg = 0; mg < 8; ++mg)
#pragma unroll
      for (int nf = 0; nf < 4; ++nf){
        int col = ntile_cur*256 + wn*64 + nf*16 + fr;
        float bv = bp[col];
        int row0 = rtile*256 + wm*128 + mg*16 + (l>>4)*4;
#pragma unroll
        for (int rg = 0; rg < 4; ++rg)
          out[(size_t)(row0+rg)*1024 + col] = acc[mg][nf][rg] + bv;
      }
  }
}

extern "C" void kernel_launch(void* const* d_in, const int* in_sizes, int n_in,
                              void* d_out, int out_size, void* d_ws, size_t ws_size,
                              hipStream_t stream)
{
  const float* x  = (const float*)d_in[0];
  const float* wh = (const float*)d_in[1];
  const float* bh = (const float*)d_in[2];
  const float* ww = (const float*)d_in[3];
  const float* bw = (const float*)d_in[4];
  const float* wd = (const float*)d_in[5];
  const float* bd = (const float*)d_in[6];
  const float* wc = (const float*)d_in[7];
  const float* bc = (const float*)d_in[8];
  const float* w1 = (const float*)d_in[9];
  const float* b1 = (const float*)d_in[10];
  const float* w2 = (const float*)d_in[11];
  const float* b2 = (const float*)d_in[12];
  const float* wp = (const float*)d_in[13];
  const float* bp = (const float*)d_in[14];
  char* ws = (char*)d_ws;
  char* ob = (char*)d_out;

  // ws layout (within previously-proven ~202.3 MiB footprint):
  u16*   xbf   = (u16*)(ws);                       // 64 MiB bf16 x; becomes mix after branch GEMMs
  u16*   hbuf  = (u16*)(ws + 67108864);            // 64 MiB (canonical layout)
  u16*   wbuf  = (u16*)(ws + 134217728);           // 64 MiB (canonical layout)
  u16*   wT    = (u16*)(ws + 201326592);           // 5 x 2 MiB bf16 W^T
  float* a_sum = (float*)(ws + 211812352);         // 32 KiB
  float* alpha = (float*)(ws + 211845120);         // 128 KiB
  float* z1g   = (float*)(ws + 211976192);         // 8 KiB
  u16*   mixb  = xbf;

  // d_out used as scratch:
  //  phase 1 (before branch GEMMs): P-partials / P arrays / reduced weights
  float* PwP  = (float*)(ob);                      // 8 MiB
  float* PdP  = (float*)(ob + 8388608);            // 8 MiB
  float* P_h  = (float*)(ob + 16777216);           // 512 KiB
  float* P_w  = (float*)(ob + 17301504);           // 512 KiB
  float* P_d  = (float*)(ob + 17825792);           // 512 KiB
  float* wred = (float*)(ob + 18350080);           // 768 KiB
  //  phase 2 (branch GEMMs .. mix): c and d branch buffers (canonical layout)
  u16*   cbuf = (u16*)ob;                          // 64 MiB
  u16*   dbuf = (u16*)(ob + 67108864);             // 64 MiB
  //  phase 3: final f32 output written directly to d_out
  float* outp = (float*)d_out;

  k_transpose  <<<dim3(32, 32, 5), dim3(32, 8), 0, stream>>>(wh, ww, wd, wc, wp, wT);
  k_psum       <<<dim3(8, 8, 8),   256, 0, stream>>>(x, xbf, P_h, PwP, PdP);
  k_psum2      <<<dim3(512),       256, 0, stream>>>(PwP, PdP, P_w, P_d);
  k_wred       <<<dim3(256, 3),    256, 0, stream>>>(wh, ww, wd, wred);
  k_asum       <<<dim3(8, 8),      256, 0, stream>>>(P_h, P_w, P_d, wred, wc, bh, bw, bd, bc, a_sum);
  k_mlp1       <<<dim3(8),         256, 0, stream>>>(a_sum, w1, b1, z1g);
  k_mlp2       <<<dim3(8, 8),      128, 0, stream>>>(z1g, w2, b2, alpha);
  k_branch_gemm<<<dim3(256),       512, 0, stream>>>(xbf, wT, bh, bw, bd, bc,
                                                     hbuf, wbuf, dbuf, cbuf);
  k_mix        <<<dim3(16384),     256, 0, stream>>>(hbuf, wbuf, dbuf, cbuf, mixb, alpha);
  k_final_gemm <<<dim3(256),       512, 0, stream>>>(mixb, wT + 4*1048576, bp, outp);
  (void)in_sizes; (void)n_in; (void)out_size; (void)ws_size;
}

// Round 6
// 896.502 us; speedup vs baseline: 1.1129x; 1.1129x over previous
//
#include <hip/hip_runtime.h>
#include <cstdint>
#include <cstddef>

typedef unsigned short u16;
typedef __attribute__((ext_vector_type(8))) __bf16 bf16x8;
typedef __attribute__((ext_vector_type(4))) float f32x4;
typedef __attribute__((ext_vector_type(4))) unsigned int u32x4;

__device__ __forceinline__ float bf2f(u16 u){
  union { unsigned int i; float f; } x; x.i = ((unsigned int)u) << 16; return x.f;
}
__device__ __forceinline__ u16 f2bf(float f){
  union { float f; unsigned int i; } x; x.f = f;
  unsigned int i = x.i;
  return (u16)((i + 0x7fffu + ((i >> 16) & 1u)) >> 16);
}
__device__ __forceinline__ void load_lds16(const u16* g, u16* l){
  __builtin_amdgcn_global_load_lds((const __attribute__((address_space(1))) void*)g,
                                   (__attribute__((address_space(3))) void*)l, 16, 0, 0);
}

// ---------------- K0: transpose+cast 5 weights (1024x1024 f32 -> bf16 W^T) ----------------
__global__ __launch_bounds__(256) void k_transpose(
    const float* __restrict__ wh, const float* __restrict__ ww,
    const float* __restrict__ wd, const float* __restrict__ wc,
    const float* __restrict__ wp, u16* __restrict__ wT)
{
  __shared__ u16 tile[32][33];
  const float* src = (blockIdx.z==0)?wh:(blockIdx.z==1)?ww:(blockIdx.z==2)?wd:(blockIdx.z==3)?wc:wp;
  u16* dst = wT + (size_t)blockIdx.z * 1048576;
  int x = blockIdx.x*32 + threadIdx.x;
  int y0 = blockIdx.y*32;
  for (int i = threadIdx.y; i < 32; i += 8)
    tile[i][threadIdx.x] = f2bf(src[(size_t)(y0+i)*1024 + x]);
  __syncthreads();
  int x2 = y0 + threadIdx.x;
  int y2 = blockIdx.x*32;
  for (int i = threadIdx.y; i < 32; i += 8)
    dst[(size_t)(y2+i)*1024 + x2] = tile[threadIdx.x][i];
}

// ---------------- K1: partial sums over 2 axes (f32, exact) + fused x->bf16 cast ----------------
__global__ __launch_bounds__(256) void k_psum(
    const float* __restrict__ x, u16* __restrict__ xbf, float* __restrict__ P_h,
    float* __restrict__ PwP, float* __restrict__ PdP)
{
  const int b = blockIdx.x, cs = blockIdx.y, hg = blockIdx.z;
  const int th = threadIdx.x >> 7, tc = threadIdx.x & 127;
  const int h = hg*2 + th, c = cs*128 + tc;
  const size_t base = ((size_t)b<<22) + ((size_t)h<<18) + c;
  const float* xb = x + base;
  u16* xo = xbf + base;
  float sh = 0.f;
  float aW[16] = {}, aD[16] = {};
#pragma unroll
  for (int w = 0; w < 16; ++w)
#pragma unroll
    for (int d = 0; d < 16; ++d){
      float v = xb[(w<<14) + (d<<10)];
      xo[(w<<14) + (d<<10)] = f2bf(v);
      sh += v; aW[w] += v; aD[d] += v;
    }
  P_h[(size_t)((b<<4)+h)*1024 + c] = sh;
  const int part = hg*2 + th;     // 0..15
  float* pw = PwP + ((size_t)part<<17) + ((size_t)b<<14) + c;
  float* pd = PdP + ((size_t)part<<17) + ((size_t)b<<14) + c;
#pragma unroll
  for (int w = 0; w < 16; ++w) pw[w<<10] = aW[w];
#pragma unroll
  for (int d = 0; d < 16; ++d) pd[d<<10] = aD[d];
}

__global__ __launch_bounds__(256) void k_psum2(
    const float* __restrict__ PwP, const float* __restrict__ PdP,
    float* __restrict__ P_w, float* __restrict__ P_d)
{
  int idx = blockIdx.x*256 + threadIdx.x;   // 0..131071
  float s = 0.f, t = 0.f;
#pragma unroll
  for (int p = 0; p < 16; ++p){ s += PwP[(size_t)p*131072 + idx]; t += PdP[(size_t)p*131072 + idx]; }
  P_w[idx] = s; P_d[idx] = t;
}

// ---------------- K3: reduced weights  wred[j][k][S] = sum_i w_j[k][i*64+S] ----------------
__global__ __launch_bounds__(256) void k_wred(
    const float* __restrict__ wh, const float* __restrict__ ww, const float* __restrict__ wd,
    float* __restrict__ wred)
{
  const float* src = (blockIdx.y==0)?wh:(blockIdx.y==1)?ww:wd;
  int idx = blockIdx.x*256 + threadIdx.x;   // 0..65535
  int k = idx >> 6, S = idx & 63;
  float s = 0.f;
#pragma unroll
  for (int i = 0; i < 16; ++i) s += src[(size_t)k*1024 + i*64 + S];
  wred[(size_t)blockIdx.y*65536 + idx] = s;
}

// ---------------- K4: a_sum[b][c] = sum over positions of (h+w+d+c branches) ----------------
__global__ __launch_bounds__(256) void k_asum(
    const float* __restrict__ P_h, const float* __restrict__ P_w, const float* __restrict__ P_d,
    const float* __restrict__ wred, const float* __restrict__ wc,
    const float* __restrict__ bhv, const float* __restrict__ bwv,
    const float* __restrict__ bdv, const float* __restrict__ bcv,
    float* __restrict__ a_sum)
{
  const int b = blockIdx.x, cs = blockIdx.y, tid = threadIdx.x;
  const int tc = tid & 127, ti = tid >> 7;
  const int c = cs*128 + tc, sg = c >> 6, S = c & 63;
  __shared__ float xbar[1024];
  __shared__ float red[2][128];
  for (int k = tid; k < 1024; k += 256){
    float s = 0.f;
#pragma unroll
    for (int hh = 0; hh < 16; ++hh) s += P_h[(size_t)(b*16+hh)*1024 + k];
    xbar[k] = s;
  }
  __syncthreads();
  const float* Ph = P_h + (size_t)b*16384;
  const float* Pw = P_w + (size_t)b*16384;
  const float* Pd = P_d + (size_t)b*16384;
  const float* whr = wred, *wwr = wred + 65536, *wdr = wred + 131072;
  float acc = 0.f;
  for (int i = ti*8; i < ti*8 + 8; ++i){
#pragma unroll 8
    for (int si = 0; si < 64; ++si){
      int k = i*64 + si;
      acc += Ph[i*1024 + sg*64 + si] * whr[(size_t)k*64 + S]
           + Pw[i*1024 + sg*64 + si] * wwr[(size_t)k*64 + S]
           + Pd[i*1024 + sg*64 + si] * wdr[(size_t)k*64 + S];
    }
  }
#pragma unroll 8
  for (int k = ti*512; k < ti*512 + 512; ++k) acc += xbar[k] * wc[(size_t)k*1024 + c];
  red[ti][tc] = acc;
  __syncthreads();
  if (ti == 0){
    float bs = 0.f;
#pragma unroll
    for (int i = 0; i < 16; ++i) bs += bhv[i*64+S] + bwv[i*64+S] + bdv[i*64+S];
    a_sum[b*1024 + c] = red[0][tc] + red[1][tc] + 4096.f*bcv[c] + 256.f*bs;
  }
}

// ---------------- K5a: z1 = gelu(mean @ w1 + b1), k-parallel ----------------
__global__ __launch_bounds__(1024) void k_mlp1(
    const float* __restrict__ a_sum, const float* __restrict__ w1,
    const float* __restrict__ b1, float* __restrict__ z1g)
{
  const int b = blockIdx.x, tid = threadIdx.x;
  const int j = tid & 255, ks = tid >> 8;     // 4 k-slices
  __shared__ float af[1024];
  __shared__ float part[4][256];
  af[tid] = a_sum[b*1024 + tid] * (1.0f/4096.0f);
  __syncthreads();
  float acc = 0.f;
#pragma unroll 8
  for (int k = ks*256; k < ks*256 + 256; ++k) acc += af[k] * w1[(size_t)k*256 + j];
  part[ks][j] = acc;
  __syncthreads();
  if (ks == 0){
    float a = part[0][j] + part[1][j] + part[2][j] + part[3][j] + b1[j];
    z1g[b*256 + j] = 0.5f * a * (1.0f + erff(a * 0.70710678118654752f));
  }
}

// ---------------- K5b: z2 = z1 @ w2 + b2 ; softmax over 4 branch slots ----------------
__global__ __launch_bounds__(128) void k_mlp2(
    const float* __restrict__ z1g, const float* __restrict__ w2,
    const float* __restrict__ b2, float* __restrict__ alpha)
{
  const int b = blockIdx.x, js = blockIdx.y, tid = threadIdx.x;
  __shared__ float z1[256];
  z1[tid] = z1g[b*256 + tid];
  z1[tid+128] = z1g[b*256 + tid + 128];
  __syncthreads();
  const int cch = js*128 + tid;       // channel 0..1023
  const int j0 = cch*4;
  f32x4 acc = *(const f32x4*)(b2 + j0);
#pragma unroll 8
  for (int k = 0; k < 256; ++k){
    f32x4 wv4 = *(const f32x4*)(w2 + (size_t)k*4096 + j0);
    float z = z1[k];
    acc[0] += z*wv4[0]; acc[1] += z*wv4[1]; acc[2] += z*wv4[2]; acc[3] += z*wv4[3];
  }
  float m = fmaxf(fmaxf(acc[0], acc[1]), fmaxf(acc[2], acc[3]));
  float e0 = expf(acc[0]-m), e1 = expf(acc[1]-m), e2 = expf(acc[2]-m), e3 = expf(acc[3]-m);
  float inv = 1.0f / (e0+e1+e2+e3);
  alpha[0*8192 + b*1024 + cch] = e0*inv;
  alpha[1*8192 + b*1024 + cch] = e1*inv;
  alpha[2*8192 + b*1024 + cch] = e2*inv;
  alpha[3*8192 + b*1024 + cch] = e3*inv;
}

// ============ 256x256 MERGED-phase GEMM template (h0+h1 fused: 12 ds_read + 32 MFMA/phase) ============
// Same LDS geometry/swizzle/stage skeleton as the verified round-4 kernel; phases h0/h1 of one
// (kk,buf) share bf fragments -> merged, halving barriers and lgkm drains (4 phases per 2 k-tiles).
// vmcnt(4) at merged phases 2 & 4 (in-flight 12 -> completes the 8 oldest = next buffer's data).

#define STAGE_A(buf, kk, kt) \
  load_lds16(gA0 + (size_t)(kt)*strideK + (kk)*32, sA + (buf)*16384 + (kk)*8192); \
  load_lds16(gA1 + (size_t)(kt)*strideK + (kk)*32, sA + (buf)*16384 + (kk)*8192 + 4096)
#define STAGE_B(buf, kk, kt) \
  load_lds16(gB0 + (kt)*64 + (kk)*32, sB + (buf)*16384 + (kk)*8192); \
  load_lds16(gB1 + (kt)*64 + (kk)*32, sB + (buf)*16384 + (kk)*8192 + 4096)
#define STAGE_AB(buf, kk, kt) STAGE_A(buf, kk, kt); STAGE_B(buf, kk, kt)

#define MPHASE(kk, buf, STAGE_STMT, VM) do{ \
  const u16* ar_ = ldsA + (buf)*16384 + (kk)*8192 + ardoff; \
  const u16* br_ = ldsB + (buf)*16384 + (kk)*8192 + brdoff; \
  bf16x8 af_[8], bf_[4]; \
  _Pragma("unroll") for (int m_ = 0; m_ < 4; ++m_){ \
    af_[m_]   = *(const bf16x8*)(ar_ + m_*512); \
    af_[4+m_] = *(const bf16x8*)(ar_ + 2048 + m_*512); \
  } \
  _Pragma("unroll") for (int n_ = 0; n_ < 4; ++n_) bf_[n_] = *(const bf16x8*)(br_ + n_*512); \
  STAGE_STMT; \
  if (VM == 1) asm volatile("s_waitcnt vmcnt(4)" ::: "memory"); \
  if (VM == 2) asm volatile("s_waitcnt vmcnt(0)" ::: "memory"); \
  __builtin_amdgcn_s_barrier(); \
  asm volatile("s_waitcnt lgkmcnt(0)" ::: "memory"); \
  __builtin_amdgcn_sched_barrier(0); \
  __builtin_amdgcn_s_setprio(1); \
  _Pragma("unroll") for (int m_ = 0; m_ < 4; ++m_) \
    _Pragma("unroll") for (int n_ = 0; n_ < 4; ++n_){ \
      acc[m_][n_]   = __builtin_amdgcn_mfma_f32_16x16x32_bf16(af_[m_],   bf_[n_], acc[m_][n_],   0, 0, 0); \
      acc[4+m_][n_] = __builtin_amdgcn_mfma_f32_16x16x32_bf16(af_[4+m_], bf_[n_], acc[4+m_][n_], 0, 0, 0); \
    } \
  __builtin_amdgcn_s_setprio(0); \
  __builtin_amdgcn_s_barrier(); \
}while(0)

#define GEMM_PROLOGUE() do{ \
  load_lds16(gA0, sA);                 load_lds16(gA1, sA + 4096); \
  load_lds16(gB0, sB);                 load_lds16(gB1, sB + 4096); \
  load_lds16(gA0 + 32, sA + 8192);     load_lds16(gA1 + 32, sA + 8192 + 4096); \
  load_lds16(gB0 + 32, sB + 8192);     load_lds16(gB1 + 32, sB + 8192 + 4096); \
  load_lds16(gA0 + strideK, sA + 16384);   load_lds16(gA1 + strideK, sA + 16384 + 4096); \
  load_lds16(gB0 + 64, sB + 16384);        load_lds16(gB1 + 64, sB + 16384 + 4096); \
  asm volatile("s_waitcnt vmcnt(4)" ::: "memory"); \
  __builtin_amdgcn_s_barrier(); \
}while(0)

#define GEMM_MAINLOOP() \
  for (int i = 0; i < 7; ++i){ \
    const int t1 = 2*i + 1, t2 = 2*i + 2, t3 = 2*i + 3; \
    MPHASE(0,0, STAGE_AB(1,1,t1), 0); \
    MPHASE(1,0, STAGE_AB(0,0,t2), 1); \
    MPHASE(0,1, STAGE_AB(0,1,t2), 0); \
    MPHASE(1,1, STAGE_AB(1,0,t3), 1); \
  } \
  MPHASE(0,0, STAGE_AB(1,1,15), 0); \
  MPHASE(1,0, (void)0, 2); \
  MPHASE(0,1, (void)0, 0); \
  MPHASE(1,1, (void)0, 0);

// ---------------- K6: branch GEMMs (h,w,d,c), 256x256 merged-phase, canonical epilogue ----------------
__global__ __launch_bounds__(512, 2) void k_branch_gemm(
    const u16* __restrict__ xbf, const u16* __restrict__ wT,
    const float* __restrict__ bh, const float* __restrict__ bw,
    const float* __restrict__ bd, const float* __restrict__ bc,
    u16* __restrict__ hbuf, u16* __restrict__ wbuf,
    u16* __restrict__ dbuf, u16* __restrict__ cbuf)
{
  // XCD-bijective swizzle: 2048 blocks = 8 XCDs x 256; logical = branch(4) x rtile(128) x ntile(4)
  const int p = blockIdx.x;
  const int id = (p & 7) * 256 + (p >> 3);
  const int ntile  = id & 3;
  const int rtile  = (id >> 2) & 127;
  const int branch = id >> 9;

  const int tid = threadIdx.x;
  const int wv = tid >> 6, l = tid & 63;

  __shared__ __align__(16) u16 ldsA[32768];   // 64 KiB
  __shared__ __align__(16) u16 ldsB[32768];   // 64 KiB

  const u16* wsel = wT + (size_t)branch * 1048576;
  const float* bias = (branch==0)?bh:(branch==1)?bw:(branch==2)?bd:bc;
  u16* obuf         = (branch==0)?hbuf:(branch==1)?wbuf:(branch==2)?dbuf:cbuf;

  const int lr = l >> 2;
  const int qg = ((l & 3) ^ ((lr >> 1) & 3)) * 8;   // T2 swizzle on global source
  int strideK;
  size_t cb0, cb1;
  {
    const int q1 = rtile & 15, b_ = rtile >> 4;
    const size_t q2a = wv, q2b = wv + 8;      // q2 for j=0 / j=1
    if (branch == 0){
      cb0 = ((size_t)b_<<22) + (q2a<<14) + ((size_t)q1<<6);
      cb1 = ((size_t)b_<<22) + (q2b<<14) + ((size_t)q1<<6);
      strideK = 262144;
    } else if (branch == 1){
      cb0 = ((size_t)b_<<22) + ((size_t)q1<<18) + (q2a<<6);
      cb1 = ((size_t)b_<<22) + ((size_t)q1<<18) + (q2b<<6);
      strideK = 16384;
    } else if (branch == 2){
      cb0 = ((size_t)b_<<22) + ((size_t)q1<<18) + (q2a<<14);
      cb1 = ((size_t)b_<<22) + ((size_t)q1<<18) + (q2b<<14);
      strideK = 1024;
    } else {
      size_t r0 = (size_t)(rtile*256 + wv*16);
      cb0 = r0 << 10; cb1 = (r0 + 128) << 10;
      strideK = 64;
    }
  }
  const int rsh = (branch == 2) ? 6 : 10;
  const u16* gA0 = xbf + cb0 + ((size_t)lr << rsh) + qg;
  const u16* gA1 = xbf + cb1 + ((size_t)lr << rsh) + qg;
  const u16* gB0 = wsel + (size_t)(ntile*256 + wv*16 + lr) * 1024 + qg;
  const u16* gB1 = gB0 + 128*1024;
  u16* sA = ldsA + wv*512;
  u16* sB = ldsB + wv*512;

  const int wm = wv >> 2, wn = wv & 3;
  const int fr = l & 15;
  const int cswz = ((l >> 4) ^ ((fr >> 1) & 3)) * 8;
  const int ardoff = (wm*128 + fr)*32 + cswz;
  const int brdoff = (wn*64  + fr)*32 + cswz;
  f32x4 acc[8][4] = {};

  GEMM_PROLOGUE();
  GEMM_MAINLOOP();

  // ---- epilogue: write CANONICAL position-major layout (b,H,W,D)x1024 + c ----
  const int bb_ = rtile >> 4, p1 = rtile & 15;
  int sc, s1, s2, s3;
  if      (branch==0){ sc=18; s1=6;  s2=14; s3=10; }
  else if (branch==1){ sc=14; s1=18; s2=6;  s3=10; }
  else if (branch==2){ sc=10; s1=18; s2=14; s3=6;  }
  else               { sc=6;  s1=18; s2=14; s3=10; }
#pragma unroll
  for (int mg = 0; mg < 8; ++mg){
    const int p2 = wm*8 + mg;
#pragma unroll
    for (int nf = 0; nf < 4; ++nf){
      int col = ntile*256 + wn*64 + nf*16 + fr;
      int ch = col >> 6, cl = col & 63;
      float bv = bias[col];
      size_t base = ((size_t)bb_<<22) | ((size_t)p1<<s1) | ((size_t)ch<<sc)
                  | ((size_t)p2<<s2) | (size_t)cl;
#pragma unroll
      for (int rg = 0; rg < 4; ++rg){
        int p3 = (l>>4)*4 + rg;
        obuf[base + ((size_t)p3<<s3)] = f2bf(acc[mg][nf][rg] + bv);
      }
    }
  }
}

// ---------------- K7: mix = a0*h + a1*w + a2*d + a3*c -> bf16 (all canonical, pure stream) ----------------
__global__ __launch_bounds__(256) void k_mix(
    const u16* __restrict__ hbuf, const u16* __restrict__ wbuf,
    const u16* __restrict__ dbuf, const u16* __restrict__ cbuf,
    u16* __restrict__ mix, const float* __restrict__ alpha)
{
  int idx = blockIdx.x*256 + threadIdx.x;   // 0..4194303
  int p  = idx >> 7;
  int c0 = (idx & 127) << 3;
  int b = p >> 12;
  size_t off = ((size_t)p << 10) + c0;
  union { u32x4 v; u16 u[8]; } hv, wv, dv, cv, mv;
  hv.v = *(const u32x4*)(hbuf + off);
  wv.v = *(const u32x4*)(wbuf + off);
  dv.v = *(const u32x4*)(dbuf + off);
  cv.v = *(const u32x4*)(cbuf + off);
  union { f32x4 f[2]; float a[8]; } a0, a1, a2, a3;
  const float* ab = alpha + b*1024 + c0;
  a0.f[0] = *(const f32x4*)(ab);         a0.f[1] = *(const f32x4*)(ab + 4);
  a1.f[0] = *(const f32x4*)(ab + 8192);  a1.f[1] = *(const f32x4*)(ab + 8196);
  a2.f[0] = *(const f32x4*)(ab + 16384); a2.f[1] = *(const f32x4*)(ab + 16388);
  a3.f[0] = *(const f32x4*)(ab + 24576); a3.f[1] = *(const f32x4*)(ab + 24580);
#pragma unroll
  for (int e = 0; e < 8; ++e){
    float m = a0.a[e]*bf2f(hv.u[e]) + a1.a[e]*bf2f(wv.u[e])
            + a2.a[e]*bf2f(dv.u[e]) + a3.a[e]*bf2f(cv.u[e]);
    mv.u[e] = f2bf(m);
  }
  *(u32x4*)(mix + off) = mv.v;
}

// ---------------- K8: out(f32) = mix(bf16) @ wp + bp   (256x256 merged-phase) ----------------
__global__ __launch_bounds__(512, 2) void k_final_gemm(
    const u16* __restrict__ A, const u16* __restrict__ wpT,
    const float* __restrict__ bp, float* __restrict__ out)
{
  // XCD-bijective swizzle: 512 blocks = 8 x 64; logical = rtile(128) x ntile(4)
  const int p = blockIdx.x;
  const int id = (p & 7) * 64 + (p >> 3);
  const int ntile = id & 3;
  const int rtile = id >> 2;

  const int tid = threadIdx.x;
  const int wv = tid >> 6, l = tid & 63;

  __shared__ __align__(16) u16 ldsA[32768];
  __shared__ __align__(16) u16 ldsB[32768];

  const int lr = l >> 2;
  const int qg = ((l & 3) ^ ((lr >> 1) & 3)) * 8;   // T2 swizzle on global source
  const int strideK = 64;
  const size_t r0 = (size_t)(rtile*256 + wv*16);
  const u16* gA0 = A + (r0 << 10) + ((size_t)lr << 10) + qg;
  const u16* gA1 = A + ((r0 + 128) << 10) + ((size_t)lr << 10) + qg;
  const u16* gB0 = wpT + (size_t)(ntile*256 + wv*16 + lr) * 1024 + qg;
  const u16* gB1 = gB0 + 128*1024;
  u16* sA = ldsA + wv*512;
  u16* sB = ldsB + wv*512;

  const int wm = wv >> 2, wn = wv & 3;
  const int fr = l & 15;
  const int cswz = ((l >> 4) ^ ((fr >> 1) & 3)) * 8;
  const int ardoff = (wm*128 + fr)*32 + cswz;
  const int brdoff = (wn*64  + fr)*32 + cswz;
  f32x4 acc[8][4] = {};

  GEMM_PROLOGUE();
  GEMM_MAINLOOP();

#pragma unroll
  for (int mg = 0; mg < 8; ++mg)
#pragma unroll
    for (int nf = 0; nf < 4; ++nf){
      int col = ntile*256 + wn*64 + nf*16 + fr;
      float bv = bp[col];
      int row0 = rtile*256 + wm*128 + mg*16 + (l>>4)*4;
#pragma unroll
      for (int rg = 0; rg < 4; ++rg)
        out[(size_t)(row0+rg)*1024 + col] = acc[mg][nf][rg] + bv;
    }
}

extern "C" void kernel_launch(void* const* d_in, const int* in_sizes, int n_in,
                              void* d_out, int out_size, void* d_ws, size_t ws_size,
                              hipStream_t stream)
{
  const float* x  = (const float*)d_in[0];
  const float* wh = (const float*)d_in[1];
  const float* bh = (const float*)d_in[2];
  const float* ww = (const float*)d_in[3];
  const float* bw = (const float*)d_in[4];
  const float* wd = (const float*)d_in[5];
  const float* bd = (const float*)d_in[6];
  const float* wc = (const float*)d_in[7];
  const float* bc = (const float*)d_in[8];
  const float* w1 = (const float*)d_in[9];
  const float* b1 = (const float*)d_in[10];
  const float* w2 = (const float*)d_in[11];
  const float* b2 = (const float*)d_in[12];
  const float* wp = (const float*)d_in[13];
  const float* bp = (const float*)d_in[14];
  char* ws = (char*)d_ws;
  char* ob = (char*)d_out;

  // ws layout (within previously-proven ~202.3 MiB footprint):
  u16*   xbf   = (u16*)(ws);                       // 64 MiB bf16 x; becomes mix after branch GEMMs
  u16*   hbuf  = (u16*)(ws + 67108864);            // 64 MiB (canonical layout)
  u16*   wbuf  = (u16*)(ws + 134217728);           // 64 MiB (canonical layout)
  u16*   wT    = (u16*)(ws + 201326592);           // 5 x 2 MiB bf16 W^T
  float* a_sum = (float*)(ws + 211812352);         // 32 KiB
  float* alpha = (float*)(ws + 211845120);         // 128 KiB
  float* z1g   = (float*)(ws + 211976192);         // 8 KiB
  u16*   mixb  = xbf;

  // d_out used as scratch:
  //  phase 1 (before branch GEMMs): P-partials / P arrays / reduced weights
  float* PwP  = (float*)(ob);                      // 8 MiB
  float* PdP  = (float*)(ob + 8388608);            // 8 MiB
  float* P_h  = (float*)(ob + 16777216);           // 512 KiB
  float* P_w  = (float*)(ob + 17301504);           // 512 KiB
  float* P_d  = (float*)(ob + 17825792);           // 512 KiB
  float* wred = (float*)(ob + 18350080);           // 768 KiB
  //  phase 2 (branch GEMMs .. mix): c and d branch buffers (canonical layout)
  u16*   cbuf = (u16*)ob;                          // 64 MiB
  u16*   dbuf = (u16*)(ob + 67108864);             // 64 MiB
  //  phase 3: final f32 output written directly to d_out
  float* outp = (float*)d_out;

  k_transpose  <<<dim3(32, 32, 5), dim3(32, 8), 0, stream>>>(wh, ww, wd, wc, wp, wT);
  k_psum       <<<dim3(8, 8, 8),   256, 0, stream>>>(x, xbf, P_h, PwP, PdP);
  k_psum2      <<<dim3(512),       256, 0, stream>>>(PwP, PdP, P_w, P_d);
  k_wred       <<<dim3(256, 3),    256, 0, stream>>>(wh, ww, wd, wred);
  k_asum       <<<dim3(8, 8),      256, 0, stream>>>(P_h, P_w, P_d, wred, wc, bh, bw, bd, bc, a_sum);
  k_mlp1       <<<dim3(8),         1024, 0, stream>>>(a_sum, w1, b1, z1g);
  k_mlp2       <<<dim3(8, 8),      128, 0, stream>>>(z1g, w2, b2, alpha);
  k_branch_gemm<<<dim3(2048),      512, 0, stream>>>(xbf, wT, bh, bw, bd, bc,
                                                     hbuf, wbuf, dbuf, cbuf);
  k_mix        <<<dim3(16384),     256, 0, stream>>>(hbuf, wbuf, dbuf, cbuf, mixb, alpha);
  k_final_gemm <<<dim3(512),       512, 0, stream>>>(mixb, wT + 4*1048576, bp, outp);
  (void)in_sizes; (void)n_in; (void)out_size; (void)ws_size;
}